// Round 1
// 675.571 us; speedup vs baseline: 1.2442x; 1.2442x over previous
//
#include <hip/hip_runtime.h>

#define R 32
#define MT 8      // m-tiles (16 rows each) per wave
#define LDST 68   // LDS row stride in floats: 16B-aligned, bank-spread

typedef _Float16 f16x8 __attribute__((ext_vector_type(8)));
typedef float fx4 __attribute__((ext_vector_type(4)));
typedef float fx8 __attribute__((ext_vector_type(8)));

// ws layout: ws[0:32] = s1 = colsum(U1), ws[32:64] = s0 = colsum(U0)
__global__ __launch_bounds__(1024) void colsum_kernel(
    const float* __restrict__ U0, int n0rows,
    const float* __restrict__ U1, int n1rows,
    float* __restrict__ ws)
{
    const float* U = (blockIdx.x == 0) ? U1 : U0;
    int rows       = (blockIdx.x == 0) ? n1rows : n0rows;
    float* out     = ws + blockIdx.x * R;

    int c = threadIdx.x & (R - 1);   // column 0..31
    int g = threadIdx.x >> 5;        // group 0..31

    float acc = 0.f;
    for (int r = g; r < rows; r += 32)
        acc += U[(size_t)r * R + c];

    __shared__ float red[32][R + 1];
    red[g][c] = acc;
    __syncthreads();
    for (int off = 16; off > 0; off >>= 1) {
        if (g < off) red[g][c] += red[g + off][c];
        __syncthreads();
    }
    if (g == 0) out[c] = red[0][c];
}

// V[p][n] = sum_k pt[p][k] * (s[k]*U[n][k])  via mfma_f32_16x16x32_f16.
// K=32 == R, so one MFMA per 16x16 tile. Wave tile: 16 rows x 64 cols.
// B-frags (scaled U, fp16) live in registers across MT m-tiles; A converted
// in-register from fp32 pt (L2/L3-resident). Store via per-wave LDS 4x4
// transpose -> contiguous 256B/16-lane nontemporal dwordx4.
__global__ __launch_bounds__(256) void mode_mfma(
    const float* __restrict__ pt,   // [P][R] fp32
    const float* __restrict__ U,    // [N][R] fp32
    const float* __restrict__ s,    // [R]
    float* __restrict__ V,          // [P][N]
    int N, int P)
{
    const int lane = threadIdx.x & 63;
    const int wave = threadIdx.x >> 6;
    const int c    = lane & 15;      // row-in-A-tile / col-in-B-tile
    const int kg   = lane >> 4;      // k-group 0..3
    const int kb   = kg * 8;         // k base (8 contiguous k per lane)
    const int c0   = blockIdx.x * 64;

    // scale for k = kb..kb+7
    const fx4* S4 = (const fx4*)s;
    fx4 sA = S4[kg * 2 + 0];
    fx4 sB = S4[kg * 2 + 1];

    // B fragments: lane supplies Ũ[n = c0+t*16+c][kb..kb+7], Ũ = U*s
    f16x8 bf[4];
#pragma unroll
    for (int t = 0; t < 4; ++t) {
        int n = c0 + t * 16 + c;
        if (n > N - 1) n = N - 1;            // clamp; masked on store
        const fx4* Up = (const fx4*)(U + (size_t)n * R + kb);
        fx4 u0 = Up[0], u1 = Up[1];
        fx8 f;
        f[0] = u0[0] * sA[0]; f[1] = u0[1] * sA[1];
        f[2] = u0[2] * sA[2]; f[3] = u0[3] * sA[3];
        f[4] = u1[0] * sB[0]; f[5] = u1[1] * sB[1];
        f[6] = u1[2] * sB[2]; f[7] = u1[3] * sB[3];
        bf[t] = __builtin_convertvector(f, f16x8);   // RNE v_cvt_f16_f32
    }

    __shared__ float lds[4][16 * LDST];   // per-wave private transpose buffer
    float* L = lds[wave];

    const int mtiles = P >> 4;            // P % 16 == 0 (50000/16 = 3125)
    const int mt0 = (blockIdx.y * 4 + wave) * MT;
    const int cc  = c * 4;
    const bool act = (c0 + cc) < N;       // N % 4 == 0, so all-or-nothing

    for (int i = 0; i < MT; ++i) {
        int mt = mt0 + i;
        if (mt >= mtiles) break;
        int p0 = mt << 4;

        // A fragment: lane supplies pt[p0 + c][kb..kb+7]
        const fx4* Ap = (const fx4*)(pt + (size_t)(p0 + c) * R + kb);
        fx4 a0 = Ap[0], a1 = Ap[1];
        fx8 fa;
        fa[0] = a0[0]; fa[1] = a0[1]; fa[2] = a0[2]; fa[3] = a0[3];
        fa[4] = a1[0]; fa[5] = a1[1]; fa[6] = a1[2]; fa[7] = a1[3];
        f16x8 af = __builtin_convertvector(fa, f16x8);

        fx4 z = {0.f, 0.f, 0.f, 0.f};
        fx4 acc0 = __builtin_amdgcn_mfma_f32_16x16x32_f16(af, bf[0], z, 0, 0, 0);
        fx4 acc1 = __builtin_amdgcn_mfma_f32_16x16x32_f16(af, bf[1], z, 0, 0, 0);
        fx4 acc2 = __builtin_amdgcn_mfma_f32_16x16x32_f16(af, bf[2], z, 0, 0, 0);
        fx4 acc3 = __builtin_amdgcn_mfma_f32_16x16x32_f16(af, bf[3], z, 0, 0, 0);

        // C/D layout (m89-verified, dtype-independent): col = lane&15,
        // row = (lane>>4)*4 + reg. Scatter into LDS [row][col].
#pragma unroll
        for (int j = 0; j < 4; ++j) {
            L[(kg * 4 + j) * LDST +  0 + c] = acc0[j];
            L[(kg * 4 + j) * LDST + 16 + c] = acc1[j];
            L[(kg * 4 + j) * LDST + 32 + c] = acc2[j];
            L[(kg * 4 + j) * LDST + 48 + c] = acc3[j];
        }
        // same-wave cross-lane LDS handoff: DS ops are in-order per wave;
        // fence compiler + HW (no __syncthreads needed, buffer is per-wave)
        asm volatile("s_waitcnt lgkmcnt(0)" ::: "memory");

        // read back row-major: lane -> row (g*4 + kg), cols cc..cc+3
        // => each 16-lane group stores one full 256B row segment
#pragma unroll
        for (int g = 0; g < 4; ++g) {
            int row = g * 4 + kg;
            fx4 v = *(const fx4*)&L[row * LDST + cc];
            if (act)
                __builtin_nontemporal_store(v,
                    (fx4*)(V + (size_t)(p0 + row) * N + c0 + cc));
        }
        // reads must land before next iteration overwrites the buffer
        asm volatile("s_waitcnt lgkmcnt(0)" ::: "memory");
    }
}

extern "C" void kernel_launch(void* const* d_in, const int* in_sizes, int n_in,
                              void* d_out, int out_size, void* d_ws, size_t ws_size,
                              hipStream_t stream) {
    const float* pt = (const float*)d_in[0];
    const float* U0 = (const float*)d_in[1];
    const float* U1 = (const float*)d_in[2];
    int P  = in_sizes[0] / R;   // 50000
    int N0 = in_sizes[1] / R;   // 2000
    int N1 = in_sizes[2] / R;   // 1000

    float* ws  = (float*)d_ws;
    float* out = (float*)d_out;

    colsum_kernel<<<dim3(2), dim3(1024), 0, stream>>>(U0, N0, U1, N1, ws);

    int mtiles = P >> 4;                          // 3125
    int gy  = (mtiles + 4 * MT - 1) / (4 * MT);   // 98
    int gx0 = (N0 + 63) / 64;                     // 32
    int gx1 = (N1 + 63) / 64;                     // 16

    // V0 = pt @ (U0*s1)^T   (s1 at ws+0)
    mode_mfma<<<dim3(gx0, gy), dim3(256), 0, stream>>>(pt, U0, ws, out, N0, P);
    // V1 = pt @ (U1*s0)^T   (s0 at ws+32)
    mode_mfma<<<dim3(gx1, gy), dim3(256), 0, stream>>>(pt, U1, ws + R,
                                                       out + (size_t)P * N0, N1, P);
}